// Round 5
// baseline (3042.394 us; speedup 1.0000x reference)
//
#include <hip/hip_runtime.h>
#include <hip/hip_bf16.h>

static constexpr int S = 64, T = 64, B = 64, E = 256, H = 256, V = 32000;
static constexpr int H4 = 4 * H;          // 1024
static constexpr int NCHUNK = 500;        // V / 64
static constexpr int NROW = (T - 1) * B;  // 4032
static constexpr int LDP = 264;           // LDS row stride (bf16 elems) for MFMA tiles

typedef short bf16x8 __attribute__((ext_vector_type(8)));
typedef float f32x4 __attribute__((ext_vector_type(4)));

__device__ __forceinline__ float sigf(float x) { return 1.0f / (1.0f + __expf(-x)); }
__device__ __forceinline__ float tanhfast(float x) { return 1.0f - 2.0f / (__expf(2.0f * x) + 1.0f); }
__device__ __forceinline__ float bflo(uint w) { return __uint_as_float(w << 16); }
__device__ __forceinline__ float bfhi(uint w) { return __uint_as_float(w & 0xffff0000u); }

// 4-bf16 dot helper (two accumulators)
__device__ __forceinline__ void qdot2(float& a0, float& a1, uint2 w0, uint2 w1,
                                      float4 v0, float4 v1) {
  a0 += bflo(w0.x) * v0.x + bfhi(w0.x) * v0.y + bflo(w0.y) * v0.z + bfhi(w0.y) * v0.w;
  a1 += bflo(w1.x) * v1.x + bfhi(w1.x) * v1.y + bflo(w1.y) * v1.z + bfhi(w1.y) * v1.w;
}

// ---- inter-block group barrier (device-scope atomics; groups placed same-XCD)
__device__ __forceinline__ void g_barrier(uint* cnt, uint target) {
  __syncthreads();
  if (threadIdx.x == 0) {
    __hip_atomic_fetch_add(cnt, 1u, __ATOMIC_RELEASE, __HIP_MEMORY_SCOPE_AGENT);
    while (__hip_atomic_load(cnt, __ATOMIC_ACQUIRE, __HIP_MEMORY_SCOPE_AGENT) < target)
      __builtin_amdgcn_s_sleep(8);
  }
  __syncthreads();
}

// ---------------- f32 -> bf16 convert (flat) ----------------
__global__ __launch_bounds__(256) void k_cvt_bf16(const float* __restrict__ src,
                                                  __hip_bfloat16* __restrict__ dst, int n) {
  int i = blockIdx.x * 256 + threadIdx.x;
  if (i < n) dst[i] = __float2bfloat16(src[i]);
}

// ---------------- f32 [N][512] -> bf16 [N][256] (first-256 slice) -------------
__global__ __launch_bounds__(256) void k_cvt_slice(const float* __restrict__ src,
                                                   __hip_bfloat16* __restrict__ dst) {
  int n = blockIdx.x, tid = threadIdx.x;
  dst[n * 256 + tid] = __float2bfloat16(src[n * 512 + tid]);
}

// ---------------- embedding gather -> bf16 [rows][256] ------------------------
__global__ __launch_bounds__(256) void k_gather(const int* __restrict__ idx,
                                                const float* __restrict__ emb,
                                                __hip_bfloat16* __restrict__ dst) {
  int r = blockIdx.x, tid = threadIdx.x;
  dst[r * 256 + tid] = __float2bfloat16(emb[idx[r] * E + tid]);
}

// ---------------- quad-k pack: dst[i][j] = bf16 src[j][off+4i..4i+3] ----------
__global__ __launch_bounds__(256) void k_pack4(const float* __restrict__ src,
                                               uint2* __restrict__ dst,
                                               int total, int jshift, int ld, int off) {
  int idx = blockIdx.x * 256 + threadIdx.x;
  if (idx >= total) return;
  int J = 1 << jshift;
  int i = idx >> jshift, j = idx & (J - 1);
  const float* s = src + (size_t)j * ld + off + 4 * i;
  float4 v = *(const float4*)s;
  ushort a = __bfloat16_as_ushort(__float2bfloat16(v.x));
  ushort b = __bfloat16_as_ushort(__float2bfloat16(v.y));
  ushort c = __bfloat16_as_ushort(__float2bfloat16(v.z));
  ushort d = __bfloat16_as_ushort(__float2bfloat16(v.w));
  uint2 o;
  o.x = (uint)a | ((uint)b << 16);
  o.y = (uint)c | ((uint)d << 16);
  dst[(size_t)i * J + j] = o;
}

// ============ shared MFMA 64x64 tile core (K=256, bf16 in, f32 acc) ===========
#define MFMA_TILE_BODY(Abase, Wbase, rb, cb)                                     \
  const int tid = threadIdx.x;                                                   \
  const int lane = tid & 63, wid = tid >> 6;                                     \
  const int wr = wid >> 1, wc = wid & 1;                                         \
  const int l15 = lane & 15, l4 = lane >> 4;                                     \
  for (int it = 0; it < 8; it++) {                                               \
    int c = it * 256 + tid;                                                      \
    int row = c >> 5, off = (c & 31) * 8;                                        \
    *(uint4*)&Asl[row * LDP + off] =                                             \
        *(const uint4*)((Abase) + (size_t)((rb) + row) * 256 + off);             \
    *(uint4*)&Bsl[row * LDP + off] =                                             \
        *(const uint4*)((Wbase) + (size_t)((cb) + row) * 256 + off);             \
  }                                                                              \
  __syncthreads();                                                               \
  f32x4 acc[2][2];                                                               \
  for (int m = 0; m < 2; m++)                                                    \
    for (int n = 0; n < 2; n++) acc[m][n] = (f32x4){0.f, 0.f, 0.f, 0.f};         \
  for (int kk = 0; kk < 8; kk++) {                                               \
    int ko = kk * 32 + l4 * 8;                                                   \
    bf16x8 a0 = *(const bf16x8*)&Asl[(wr * 32 + l15) * LDP + ko];                \
    bf16x8 a1 = *(const bf16x8*)&Asl[(wr * 32 + 16 + l15) * LDP + ko];           \
    bf16x8 b0 = *(const bf16x8*)&Bsl[(wc * 32 + l15) * LDP + ko];                \
    bf16x8 b1 = *(const bf16x8*)&Bsl[(wc * 32 + 16 + l15) * LDP + ko];           \
    acc[0][0] = __builtin_amdgcn_mfma_f32_16x16x32_bf16(a0, b0, acc[0][0], 0, 0, 0); \
    acc[0][1] = __builtin_amdgcn_mfma_f32_16x16x32_bf16(a0, b1, acc[0][1], 0, 0, 0); \
    acc[1][0] = __builtin_amdgcn_mfma_f32_16x16x32_bf16(a1, b0, acc[1][0], 0, 0, 0); \
    acc[1][1] = __builtin_amdgcn_mfma_f32_16x16x32_bf16(a1, b1, acc[1][1], 0, 0, 0); \
  }

// ---------------- generic GEMM + bias: C f32 = A x W^T + bias -----------------
__global__ __launch_bounds__(256) void k_gemm_bias(
    const __hip_bfloat16* __restrict__ A, const __hip_bfloat16* __restrict__ W,
    const float* __restrict__ bias, float* __restrict__ C, int ldc) {
  __shared__ __align__(16) ushort Asl[64 * LDP];
  __shared__ __align__(16) ushort Bsl[64 * LDP];
  const int cb = blockIdx.x * 64, rb = blockIdx.y * 64;
  MFMA_TILE_BODY((const ushort*)A, (const ushort*)W, rb, cb)
  #pragma unroll
  for (int m = 0; m < 2; m++)
    #pragma unroll
    for (int n = 0; n < 2; n++) {
      int col = cb + wc * 32 + n * 16 + l15;
      float bv = bias[col];
      #pragma unroll
      for (int r = 0; r < 4; r++) {
        int row = rb + wr * 32 + m * 16 + l4 * 4 + r;
        C[(size_t)row * ldc + col] = acc[m][n][r] + bv;
      }
    }
}

// ---------------- vocab GEMM + fused chunk logsumexp + gold capture -----------
// grid (63, 500): same-Wv-slice blocks adjacent in dispatch for L2 locality.
__global__ __launch_bounds__(256) void k_vocab_mfma(
    const __hip_bfloat16* __restrict__ outs_bf, const __hip_bfloat16* __restrict__ Wv,
    const int* __restrict__ tgt, float* __restrict__ part_max,
    float* __restrict__ part_sum, float* __restrict__ gold) {
  __shared__ __align__(16) ushort Asl[64 * LDP];
  __shared__ __align__(16) ushort Bsl[64 * LDP];
  __shared__ int goldcol[64];
  __shared__ float pm[64][2], ps[64][2];
  const int by = blockIdx.x, vb = blockIdx.y;
  const int cb = vb * 64, rb = by * 64;
  if (threadIdx.x < 64) goldcol[threadIdx.x] = tgt[(by + 1) * B + threadIdx.x];
  MFMA_TILE_BODY((const ushort*)outs_bf, (const ushort*)Wv, rb, cb)
  #pragma unroll
  for (int m = 0; m < 2; m++) {
    #pragma unroll
    for (int r = 0; r < 4; r++) {
      int row_local = wr * 32 + m * 16 + l4 * 4 + r;
      int gc = goldcol[row_local];
      #pragma unroll
      for (int n = 0; n < 2; n++) {
        int col = cb + wc * 32 + n * 16 + l15;
        if (col == gc) gold[rb + row_local] = acc[m][n][r];
      }
      float v = fmaxf(acc[m][0][r], acc[m][1][r]);
      #pragma unroll
      for (int o = 1; o < 16; o <<= 1) v = fmaxf(v, __shfl_xor(v, o));
      float e = __expf(acc[m][0][r] - v) + __expf(acc[m][1][r] - v);
      #pragma unroll
      for (int o = 1; o < 16; o <<= 1) e += __shfl_xor(e, o);
      if (l15 == 0) { pm[row_local][wc] = v; ps[row_local][wc] = e; }
    }
  }
  __syncthreads();
  if (tid < 64) {
    float m0 = pm[tid][0], m1 = pm[tid][1];
    float M = fmaxf(m0, m1);
    float Ss = ps[tid][0] * __expf(m0 - M) + ps[tid][1] * __expf(m1 - M);
    int n = rb + tid;
    part_max[(size_t)n * NCHUNK + vb] = M;
    part_sum[(size_t)n * NCHUNK + vb] = Ss;
  }
}

// ---------------- persistent encoder, K-split x2: grid 256, block 1024 --------
// id = 16*(gid>>3) + 8*m + (gid&7); gid = dir*64+b. Group = {m=0,1}, same XCD.
// zp_enc[gid][par][m][1024] f32 (double-buffered by step parity).
__global__ __launch_bounds__(1024, 4) void k_enc_persist2(
    const float* __restrict__ XwF, const float* __restrict__ XwB,
    const uint2* __restrict__ Wq_f, const uint2* __restrict__ Wq_b,
    __hip_bfloat16* __restrict__ fwd_bf, __hip_bfloat16* __restrict__ bwd_bf,
    float* __restrict__ Hfin, float* __restrict__ Cfin,
    float* __restrict__ zp_enc, uint* __restrict__ cnt_enc) {
  const int id = blockIdx.x;
  const int m = (id >> 3) & 1;
  const int gid = ((id >> 4) << 3) | (id & 7);
  const int b = gid & 63, dir = gid >> 6;
  const int tid = threadIdx.x;
  __shared__ float h_lds[256];
  __shared__ float c_lds[256];
  const uint2* Wq = dir ? Wq_b : Wq_f;
  const float* Xw = dir ? XwB : XwF;
  float* zpg = zp_enc + (size_t)gid * 4096;
  uint* cnt = cnt_enc + gid;
  if (tid < 256) { h_lds[tid] = 0.f; c_lds[tid] = 0.f; }
  __syncthreads();
  for (int st = 0; st < 64; st++) {
    const int ts = dir ? (63 - st) : st;
    float* zp = zpg + (st & 1) * 2048;
    {  // z-partial over k-half m (32 quads)
      float a0 = 0.f, a1 = 0.f;
      const uint2* wp = Wq + (size_t)(32 * m) * 1024 + tid;
      const float4* x4 = (const float4*)&h_lds[128 * m];
      #pragma unroll 8
      for (int i = 0; i < 32; i += 2)
        qdot2(a0, a1, wp[(size_t)i * 1024], wp[(size_t)(i + 1) * 1024], x4[i], x4[i + 1]);
      zp[m * 1024 + tid] = a0 + a1;
    }
    g_barrier(cnt, 2u * (uint)(st + 1));
    if (tid < 256) {  // replicated LSTM update
      const float* xw = Xw + (size_t)(ts * 64 + b) * 1024;
      float zi = zp[tid]       + zp[1024 + tid]       + xw[tid];
      float zf = zp[256 + tid] + zp[1024 + 256 + tid] + xw[256 + tid];
      float zg = zp[512 + tid] + zp[1024 + 512 + tid] + xw[512 + tid];
      float zo = zp[768 + tid] + zp[1024 + 768 + tid] + xw[768 + tid];
      float c = sigf(zf) * c_lds[tid] + sigf(zi) * tanhfast(zg);
      c_lds[tid] = c;
      float h = sigf(zo) * tanhfast(c);
      h_lds[tid] = h;
      if (m == 0) {
        __hip_bfloat16 hb = __float2bfloat16(h);
        if (dir == 0) fwd_bf[(st * 64 + b) * 256 + tid] = hb;
        else          bwd_bf[((63 - st) * 64 + b) * 256 + tid] = hb;
      }
    }
    __syncthreads();
  }
  if (tid < 256 && m == 0) {
    Hfin[(dir * 64 + b) * 256 + tid] = h_lds[tid];
    Cfin[(dir * 64 + b) * 256 + tid] = c_lds[tid];
  }
}

// ---------------- decoder init ------------------------------------------------
__global__ __launch_bounds__(256) void k_dec_init(
    const float* __restrict__ Hfin, const float* __restrict__ Cfin,
    const float* __restrict__ Wh, const float* __restrict__ Wc,
    float* __restrict__ dech0, float* __restrict__ decc0) {
  int b = blockIdx.x, tid = threadIdx.x;
  __shared__ __align__(16) float ch[512], cc[512];
  ch[tid]       = Hfin[(0 * 64 + b) * 256 + tid];
  ch[256 + tid] = Hfin[(1 * 64 + b) * 256 + tid];
  cc[tid]       = Cfin[(0 * 64 + b) * 256 + tid];
  cc[256 + tid] = Cfin[(1 * 64 + b) * 256 + tid];
  __syncthreads();
  const float* wh = Wh + tid * 512;
  const float* wc = Wc + tid * 512;
  float ah = 0, ac = 0;
  for (int k = 0; k < 512; k += 4) {
    float4 hv = *(const float4*)&ch[k];
    float4 cv = *(const float4*)&cc[k];
    float4 w1 = *(const float4*)&wh[k];
    float4 w2 = *(const float4*)&wc[k];
    ah += hv.x * w1.x + hv.y * w1.y + hv.z * w1.z + hv.w * w1.w;
    ac += cv.x * w2.x + cv.y * w2.y + cv.z * w2.z + cv.w * w2.w;
  }
  dech0[b * 256 + tid] = ah;
  decc0[b * 256 + tid] = ac;
}

// ---------------- enc_proj[b][s][j] ------------------------------------------
__global__ __launch_bounds__(256) void k_enc_proj(
    const __hip_bfloat16* __restrict__ fwd_bf, const __hip_bfloat16* __restrict__ bwd_bf,
    const float* __restrict__ Watt, __hip_bfloat16* __restrict__ encproj_bf) {
  int b = blockIdx.x, s = blockIdx.y, tid = threadIdx.x;
  __shared__ __align__(16) float eh[512];
  eh[tid]       = __bfloat162float(fwd_bf[(s * B + b) * H + tid]);
  eh[256 + tid] = __bfloat162float(bwd_bf[(s * B + b) * H + tid]);
  __syncthreads();
  const float* w = Watt + tid * 512;
  float acc = 0;
  for (int k = 0; k < 512; k += 4) {
    float4 xv = *(const float4*)&eh[k];
    float4 wv = *(const float4*)&w[k];
    acc += xv.x * wv.x + xv.y * wv.y + xv.z * wv.z + xv.w * wv.w;
  }
  encproj_bf[(b * S + s) * H + tid] = __float2bfloat16(acc);
}

// ---------------- persistent decoder, K-split x4: grid 256, block 1024 --------
// id = 32*(b>>3) + 8*q + (b&7). Group = 4 q's of b, same XCD.
// k-quarters of z: q0:h[0:128] q1:h[128:256] q2:O[0:128] q3:O[128:256].
// h,c replicated per block; zp_dec[b][q][1024]; O_g[b][256] f32 (q owns j 64q..64q+63).
__global__ __launch_bounds__(1024, 4) void k_dec_persist2(
    const float* __restrict__ YW, const uint2* __restrict__ zWq,
    const uint2* __restrict__ Wcq, const __hip_bfloat16* __restrict__ encproj_bf,
    const __hip_bfloat16* __restrict__ fwd_bf, const __hip_bfloat16* __restrict__ bwd_bf,
    const float* __restrict__ dech0, const float* __restrict__ decc0,
    __hip_bfloat16* __restrict__ outs_bf,
    float* __restrict__ zp_dec, float* __restrict__ O_g, uint* __restrict__ cnt_dec) {
  const int id = blockIdx.x;
  const int q = (id >> 3) & 3;
  const int b = ((id >> 5) << 3) | (id & 7);
  const int tid = threadIdx.x;
  __shared__ float h_lds[256], c_lds[256];
  __shared__ __align__(16) float xq[128];
  __shared__ float e_lds[64], alpha_lds[64];
  __shared__ float ap[2][512];
  __shared__ __align__(16) float xcomb[768];
  __shared__ float op[16][65];
  float* zp = zp_dec + (size_t)b * 4096;
  float* Ob = O_g + (size_t)b * 256;
  uint* cnt = cnt_dec + b;
  if (tid < 256) {
    h_lds[tid] = dech0[b * 256 + tid];
    c_lds[tid] = decc0[b * 256 + tid];
  }
  __syncthreads();
  uint inst = 0;
  for (int t = 0; t < 63; t++) {
    // ---- load O quarter for q>=2 (t==0: zeros) ----
    if (q >= 2 && tid < 128) xq[tid] = (t == 0) ? 0.f : Ob[(q - 2) * 128 + tid];
    __syncthreads();
    // ---- z-partial over k-quarter q (32 quads) ----
    {
      float a0 = 0.f, a1 = 0.f;
      const uint2* wp = zWq + (size_t)(32 * q) * 1024 + tid;
      const float4* x4 = (q < 2) ? (const float4*)&h_lds[128 * q] : (const float4*)xq;
      #pragma unroll 8
      for (int i = 0; i < 32; i += 2)
        qdot2(a0, a1, wp[(size_t)i * 1024], wp[(size_t)(i + 1) * 1024], x4[i], x4[i + 1]);
      zp[q * 1024 + tid] = a0 + a1;
    }
    inst++; g_barrier(cnt, 4u * inst);
    // ---- replicated LSTM update ----
    if (tid < 256) {
      const float* yw = YW + (size_t)(t * 64 + b) * 1024;
      float zi = zp[tid]       + zp[1024 + tid]       + zp[2048 + tid]       + zp[3072 + tid]       + yw[tid];
      float zf = zp[256 + tid] + zp[1024 + 256 + tid] + zp[2048 + 256 + tid] + zp[3072 + 256 + tid] + yw[256 + tid];
      float zg = zp[512 + tid] + zp[1024 + 512 + tid] + zp[2048 + 512 + tid] + zp[3072 + 512 + tid] + yw[512 + tid];
      float zo = zp[768 + tid] + zp[1024 + 768 + tid] + zp[2048 + 768 + tid] + zp[3072 + 768 + tid] + yw[768 + tid];
      float c = sigf(zf) * c_lds[tid] + sigf(zi) * tanhfast(zg);
      c_lds[tid] = c;
      h_lds[tid] = sigf(zo) * tanhfast(c);
    }
    __syncthreads();
    // ---- replicated attention: e[s] ----
    {
      int s = tid >> 4, q16 = tid & 15;
      const uint2* pr = (const uint2*)((const ushort*)encproj_bf + (size_t)(b * 64 + s) * 256) + q16 * 4;
      const float4* hq = (const float4*)(h_lds + q16 * 16);
      float a = 0.f;
      #pragma unroll
      for (int c = 0; c < 4; c++) {
        uint2 w = pr[c];
        float4 hv = hq[c];
        a += bflo(w.x) * hv.x + bfhi(w.x) * hv.y + bflo(w.y) * hv.z + bfhi(w.y) * hv.w;
      }
      #pragma unroll
      for (int o = 8; o > 0; o >>= 1) a += __shfl_xor(a, o);
      if (q16 == 0) e_lds[s] = a;
    }
    __syncthreads();
    if (tid < 64) {  // softmax over s (wave 0)
      float e = e_lds[tid];
      float m = e;
      #pragma unroll
      for (int o = 32; o > 0; o >>= 1) m = fmaxf(m, __shfl_xor(m, o));
      float p = __expf(e - m);
      float ss = p;
      #pragma unroll
      for (int o = 32; o > 0; o >>= 1) ss += __shfl_xor(ss, o);
      alpha_lds[tid] = p / ss;
    }
    __syncthreads();
    {  // a_t partials
      int d = tid & 511, sh = tid >> 9;
      const ushort* basep = (d < 256)
          ? ((const ushort*)fwd_bf + b * 256 + d)
          : ((const ushort*)bwd_bf + b * 256 + (d - 256));
      float a = 0.f;
      #pragma unroll 8
      for (int s = sh * 32; s < sh * 32 + 32; s++)
        a += alpha_lds[s] * __uint_as_float(((uint)basep[(size_t)s * 16384]) << 16);
      ap[sh][d] = a;
    }
    __syncthreads();
    if (tid < 512) xcomb[tid] = ap[0][tid] + ap[1][tid];
    else if (tid < 768) xcomb[tid] = h_lds[tid - 512];
    __syncthreads();
    // ---- Wcomb j-quarter: j = 64q + (tid&63), k-slice = (tid>>6)*12 quads ----
    {
      int jl = tid & 63, k16 = tid >> 6;
      const uint2* wp2 = Wcq + (64 * q + jl);
      const float4* x4 = (const float4*)xcomb;
      float a = 0.f;
      #pragma unroll 6
      for (int ii = 0; ii < 12; ii++) {
        int i = k16 * 12 + ii;
        uint2 w = wp2[(size_t)i * 256];
        float4 xv = x4[i];
        a += bflo(w.x) * xv.x + bfhi(w.x) * xv.y + bflo(w.y) * xv.z + bfhi(w.y) * xv.w;
      }
      op[k16][jl] = a;
    }
    __syncthreads();
    if (tid < 64) {
      float s = 0.f;
      #pragma unroll
      for (int k = 0; k < 16; k++) s += op[k][tid];
      float O = tanhfast(s);
      Ob[64 * q + tid] = O;
      outs_bf[(size_t)(t * 64 + b) * 256 + 64 * q + tid] = __float2bfloat16(O);
    }
    inst++; g_barrier(cnt, 4u * inst);
  }
}

// ---------------- final reduce ------------------------------------------------
__global__ __launch_bounds__(256) void k_final(
    const float* __restrict__ part_max, const float* __restrict__ part_sum,
    const float* __restrict__ gold, const int* __restrict__ tgt,
    float* __restrict__ out) {
  int b = blockIdx.x, tid = threadIdx.x;
  int tq = tid >> 2, q = tid & 3;
  __shared__ float lm[64][4], ls[64][4];
  __shared__ float red[64];
  if (tq < T - 1) {
    int n = tq * B + b;
    float m = -__builtin_inff(), s = 0;
    for (int i = q; i < NCHUNK; i += 4) {
      float pmv = part_max[(size_t)n * NCHUNK + i];
      float psv = part_sum[(size_t)n * NCHUNK + i];
      float M2 = fmaxf(m, pmv);
      s = s * __expf(m - M2) + psv * __expf(pmv - M2);
      m = M2;
    }
    lm[tq][q] = m;
    ls[tq][q] = s;
  }
  __syncthreads();
  if (tid < T - 1) {
    float M = fmaxf(fmaxf(lm[tid][0], lm[tid][1]), fmaxf(lm[tid][2], lm[tid][3]));
    float Ss = ls[tid][0] * __expf(lm[tid][0] - M) + ls[tid][1] * __expf(lm[tid][1] - M) +
               ls[tid][2] * __expf(lm[tid][2] - M) + ls[tid][3] * __expf(lm[tid][3] - M);
    float lse = M + logf(Ss);
    int g = tgt[(tid + 1) * B + b];
    red[tid] = (g != 0) ? (gold[tid * B + b] - lse) : 0.f;
  }
  if (tid == T - 1) red[T - 1] = 0.f;
  __syncthreads();
  if (tid == 0) {
    float s = 0;
    for (int i = 0; i < T - 1; i++) s += red[i];
    out[b] = s;
  }
}

extern "C" void kernel_launch(void* const* d_in, const int* in_sizes, int n_in,
                              void* d_out, int out_size, void* d_ws, size_t ws_size,
                              hipStream_t stream) {
  (void)in_sizes; (void)n_in; (void)out_size; (void)ws_size;
  const int*   src   = (const int*)  d_in[0];
  const int*   tgt   = (const int*)  d_in[1];
  const float* semb  = (const float*)d_in[2];
  const float* temb  = (const float*)d_in[3];
  const float* WihF  = (const float*)d_in[4];
  const float* WhhF  = (const float*)d_in[5];
  const float* bF    = (const float*)d_in[6];
  const float* WihB  = (const float*)d_in[7];
  const float* WhhB  = (const float*)d_in[8];
  const float* bB    = (const float*)d_in[9];
  const float* dWih  = (const float*)d_in[10];
  const float* dWhh  = (const float*)d_in[11];
  const float* db    = (const float*)d_in[12];
  const float* Wh    = (const float*)d_in[13];
  const float* Wc    = (const float*)d_in[14];
  const float* Watt  = (const float*)d_in[15];
  const float* Wcomb = (const float*)d_in[16];
  const float* Wv    = (const float*)d_in[17];
  float* out = (float*)d_out;

  char* wp = (char*)d_ws;
  auto alloc = [&](size_t bytes) -> char* {
    char* p = wp;
    wp += (bytes + 255) & ~(size_t)255;
    return p;
  };
  float* XwF  = (float*)alloc((size_t)S * B * H4 * 4);
  float* XwB  = (float*)alloc((size_t)S * B * H4 * 4);
  float* YW   = (float*)alloc((size_t)(T - 1) * B * H4 * 4);
  __hip_bfloat16* fwd_bf     = (__hip_bfloat16*)alloc((size_t)S * B * H * 2);
  __hip_bfloat16* bwd_bf     = (__hip_bfloat16*)alloc((size_t)S * B * H * 2);
  __hip_bfloat16* encproj_bf = (__hip_bfloat16*)alloc((size_t)B * S * H * 2);
  __hip_bfloat16* Ag         = (__hip_bfloat16*)alloc((size_t)S * B * E * 2);
  __hip_bfloat16* Yg         = (__hip_bfloat16*)alloc((size_t)(T - 1) * B * E * 2);
  __hip_bfloat16* WihF_bf    = (__hip_bfloat16*)alloc((size_t)H4 * E * 2);
  __hip_bfloat16* WihB_bf    = (__hip_bfloat16*)alloc((size_t)H4 * E * 2);
  __hip_bfloat16* dWih_bf    = (__hip_bfloat16*)alloc((size_t)H4 * E * 2);
  __hip_bfloat16* Wv_bf      = (__hip_bfloat16*)alloc((size_t)V * H * 2);
  __hip_bfloat16* outs_bf    = (__hip_bfloat16*)alloc((size_t)NROW * H * 2);
  uint2* Wq_f = (uint2*)alloc((size_t)64 * 1024 * 8);
  uint2* Wq_b = (uint2*)alloc((size_t)64 * 1024 * 8);
  uint2* zWq  = (uint2*)alloc((size_t)128 * 1024 * 8);
  uint2* Wcq  = (uint2*)alloc((size_t)192 * 256 * 8);
  float* part_max = (float*)alloc((size_t)NROW * NCHUNK * 4);
  float* part_sum = (float*)alloc((size_t)NROW * NCHUNK * 4);
  float* gold     = (float*)alloc((size_t)NROW * 4);
  float* Hfin  = (float*)alloc((size_t)2 * B * H * 4);
  float* Cfin  = (float*)alloc((size_t)2 * B * H * 4);
  float* dech0 = (float*)alloc((size_t)B * H * 4);
  float* decc0 = (float*)alloc((size_t)B * H * 4);
  float* zp_enc = (float*)alloc((size_t)128 * 2 * 2 * 1024 * 4);  // [gid][par][m][1024]
  float* zp_dec = (float*)alloc((size_t)64 * 4 * 1024 * 4);       // [b][q][1024]
  float* O_g    = (float*)alloc((size_t)64 * 256 * 4);
  // state region: barrier counters (must be zeroed every call)
  char* stateBase = wp;
  uint* cnt_enc = (uint*)alloc(128 * 4);
  uint* cnt_dec = (uint*)alloc(64 * 4);
  size_t stateBytes = (size_t)(wp - stateBase);
  hipMemsetAsync(stateBase, 0, stateBytes, stream);

  // converts + gathers + weight packs
  hipLaunchKernelGGL(k_cvt_bf16, dim3((H4 * E + 255) / 256), dim3(256), 0, stream,
                     WihF, WihF_bf, H4 * E);
  hipLaunchKernelGGL(k_cvt_bf16, dim3((H4 * E + 255) / 256), dim3(256), 0, stream,
                     WihB, WihB_bf, H4 * E);
  hipLaunchKernelGGL(k_cvt_slice, dim3(H4), dim3(256), 0, stream, dWih, dWih_bf);
  hipLaunchKernelGGL(k_cvt_bf16, dim3((V * H + 255) / 256), dim3(256), 0, stream,
                     Wv, Wv_bf, V * H);
  hipLaunchKernelGGL(k_gather, dim3(S * B), dim3(256), 0, stream, src, semb, Ag);
  hipLaunchKernelGGL(k_gather, dim3((T - 1) * B), dim3(256), 0, stream, tgt, temb, Yg);
  hipLaunchKernelGGL(k_pack4, dim3(64 * 1024 / 256), dim3(256), 0, stream,
                     WhhF, Wq_f, 64 * 1024, 10, 256, 0);
  hipLaunchKernelGGL(k_pack4, dim3(64 * 1024 / 256), dim3(256), 0, stream,
                     WhhB, Wq_b, 64 * 1024, 10, 256, 0);
  hipLaunchKernelGGL(k_pack4, dim3(64 * 1024 / 256), dim3(256), 0, stream,
                     dWhh, zWq, 64 * 1024, 10, 256, 0);
  hipLaunchKernelGGL(k_pack4, dim3(64 * 1024 / 256), dim3(256), 0, stream,
                     dWih, zWq + (size_t)64 * 1024, 64 * 1024, 10, 512, 256);
  hipLaunchKernelGGL(k_pack4, dim3(192 * 256 / 256), dim3(256), 0, stream,
                     Wcomb, Wcq, 192 * 256, 8, 768, 0);

  // input GEMMs (MFMA)
  hipLaunchKernelGGL(k_gemm_bias, dim3(H4 / 64, S * B / 64), dim3(256), 0, stream,
                     Ag, WihF_bf, bF, XwF, H4);
  hipLaunchKernelGGL(k_gemm_bias, dim3(H4 / 64, S * B / 64), dim3(256), 0, stream,
                     Ag, WihB_bf, bB, XwB, H4);
  hipLaunchKernelGGL(k_gemm_bias, dim3(H4 / 64, (T - 1) * B / 64), dim3(256), 0, stream,
                     Yg, dWih_bf, db, YW, H4);

  // persistent encoder (256 blocks, K-split x2 per (b,dir))
  hipLaunchKernelGGL(k_enc_persist2, dim3(256), dim3(1024), 0, stream,
                     XwF, XwB, Wq_f, Wq_b, fwd_bf, bwd_bf, Hfin, Cfin, zp_enc, cnt_enc);
  hipLaunchKernelGGL(k_dec_init, dim3(B), dim3(256), 0, stream,
                     Hfin, Cfin, Wh, Wc, dech0, decc0);
  hipLaunchKernelGGL(k_enc_proj, dim3(B, S), dim3(256), 0, stream,
                     fwd_bf, bwd_bf, Watt, encproj_bf);

  // persistent decoder (256 blocks, K-split x4 per b)
  hipLaunchKernelGGL(k_dec_persist2, dim3(256), dim3(1024), 0, stream,
                     YW, zWq, Wcq, encproj_bf, fwd_bf, bwd_bf, dech0, decc0, outs_bf,
                     zp_dec, O_g, cnt_dec);

  // vocab projection + log-softmax partials + final reduce
  hipLaunchKernelGGL(k_vocab_mfma, dim3(T - 1, NCHUNK), dim3(256), 0, stream,
                     outs_bf, Wv_bf, tgt, part_max, part_sum, gold);
  hipLaunchKernelGGL(k_final, dim3(B), dim3(256), 0, stream,
                     part_max, part_sum, gold, tgt, out);
}

// Round 6
// 2778.110 us; speedup vs baseline: 1.0951x; 1.0951x over previous
//
#include <hip/hip_runtime.h>
#include <hip/hip_bf16.h>

static constexpr int S = 64, T = 64, B = 64, E = 256, H = 256, V = 32000;
static constexpr int H4 = 4 * H;          // 1024
static constexpr int NCHUNK = 500;        // V / 64
static constexpr int NROW = (T - 1) * B;  // 4032
static constexpr int LDP = 264;           // LDS row stride (bf16) for MFMA staging tiles

typedef short bf16x8 __attribute__((ext_vector_type(8)));
typedef float f32x4 __attribute__((ext_vector_type(4)));

__device__ __forceinline__ float sigf(float x) { return 1.0f / (1.0f + __expf(-x)); }
__device__ __forceinline__ float tanhfast(float x) { return 1.0f - 2.0f / (__expf(2.0f * x) + 1.0f); }
__device__ __forceinline__ float bflo(uint w) { return __uint_as_float(w << 16); }
__device__ __forceinline__ float bfhi(uint w) { return __uint_as_float(w & 0xffff0000u); }
__device__ __forceinline__ ushort f2bu(float x) {
  return __bfloat16_as_ushort(__float2bfloat16(x));
}

// ---- simple group barrier (monotone target), agent scope ----
__device__ __forceinline__ void g_barrier(uint* cnt, uint target) {
  __syncthreads();
  if (threadIdx.x == 0) {
    __hip_atomic_fetch_add(cnt, 1u, __ATOMIC_RELEASE, __HIP_MEMORY_SCOPE_AGENT);
    while (__hip_atomic_load(cnt, __ATOMIC_ACQUIRE, __HIP_MEMORY_SCOPE_AGENT) < target)
      __builtin_amdgcn_s_sleep(1);
  }
  __syncthreads();
}

// ---- 2-level barrier for 136 blocks: 8 groups x 17 ----
__device__ __forceinline__ void dbar(uint* loc, uint* glob, int grp, int phase) {
  __syncthreads();
  if (threadIdx.x == 0) {
    uint old = __hip_atomic_fetch_add(&loc[grp], 1u, __ATOMIC_RELEASE, __HIP_MEMORY_SCOPE_AGENT);
    if (old == (uint)(17 * phase + 16))
      __hip_atomic_fetch_add(glob, 1u, __ATOMIC_RELEASE, __HIP_MEMORY_SCOPE_AGENT);
    while (__hip_atomic_load(glob, __ATOMIC_ACQUIRE, __HIP_MEMORY_SCOPE_AGENT) < (uint)(8 * (phase + 1)))
      __builtin_amdgcn_s_sleep(1);
  }
  __syncthreads();
}

// ---------------- small utility kernels ----------------
__global__ __launch_bounds__(256) void k_cvt_bf16(const float* __restrict__ src,
                                                  __hip_bfloat16* __restrict__ dst, int n) {
  int i = blockIdx.x * 256 + threadIdx.x;
  if (i < n) dst[i] = __float2bfloat16(src[i]);
}

__global__ __launch_bounds__(256) void k_cvt_slice(const float* __restrict__ src,
                                                   __hip_bfloat16* __restrict__ dst) {
  int n = blockIdx.x, tid = threadIdx.x;
  dst[n * 256 + tid] = __float2bfloat16(src[n * 512 + tid]);
}

__global__ __launch_bounds__(256) void k_gather(const int* __restrict__ idx,
                                                const float* __restrict__ emb,
                                                __hip_bfloat16* __restrict__ dst) {
  int r = blockIdx.x, tid = threadIdx.x;
  dst[r * 256 + tid] = __float2bfloat16(emb[idx[r] * E + tid]);
}

// quad-k pack: dst[i][j] = bf16 src[j][4i..4i+3]  (uint2 [K/4][J])
__global__ __launch_bounds__(256) void k_pack4(const float* __restrict__ src,
                                               uint2* __restrict__ dst,
                                               int total, int jshift, int ld, int off) {
  int idx = blockIdx.x * 256 + threadIdx.x;
  if (idx >= total) return;
  int J = 1 << jshift;
  int i = idx >> jshift, j = idx & (J - 1);
  const float* s = src + (size_t)j * ld + off + 4 * i;
  float4 v = *(const float4*)s;
  uint2 o;
  o.x = (uint)f2bu(v.x) | ((uint)f2bu(v.y) << 16);
  o.y = (uint)f2bu(v.z) | ((uint)f2bu(v.w) << 16);
  dst[(size_t)i * J + j] = o;
}

// X_dec init: par0 h = dech0, par0 O = 0
__global__ __launch_bounds__(256) void k_xdec_init(const float* __restrict__ dech0,
                                                   __hip_bfloat16* __restrict__ Xd) {
  int b = blockIdx.x, tid = threadIdx.x;
  Xd[b * 512 + tid] = __float2bfloat16(dech0[b * 256 + tid]);
  Xd[b * 512 + 256 + tid] = __float2bfloat16(0.f);
}

// ============ shared MFMA 64x64 tile core (K=256, bf16 in, f32 acc) ===========
#define MFMA_TILE_BODY(Abase, Wbase, rb, cb)                                     \
  const int tid = threadIdx.x;                                                   \
  const int lane = tid & 63, wid = tid >> 6;                                     \
  const int wr = wid >> 1, wc = wid & 1;                                         \
  const int l15 = lane & 15, l4 = lane >> 4;                                     \
  for (int it = 0; it < 8; it++) {                                               \
    int c = it * 256 + tid;                                                      \
    int row = c >> 5, off = (c & 31) * 8;                                        \
    *(uint4*)&Asl[row * LDP + off] =                                             \
        *(const uint4*)((Abase) + (size_t)((rb) + row) * 256 + off);             \
    *(uint4*)&Bsl[row * LDP + off] =                                             \
        *(const uint4*)((Wbase) + (size_t)((cb) + row) * 256 + off);             \
  }                                                                              \
  __syncthreads();                                                               \
  f32x4 acc[2][2];                                                               \
  for (int m = 0; m < 2; m++)                                                    \
    for (int n = 0; n < 2; n++) acc[m][n] = (f32x4){0.f, 0.f, 0.f, 0.f};         \
  for (int kk = 0; kk < 8; kk++) {                                               \
    int ko = kk * 32 + l4 * 8;                                                   \
    bf16x8 a0 = *(const bf16x8*)&Asl[(wr * 32 + l15) * LDP + ko];                \
    bf16x8 a1 = *(const bf16x8*)&Asl[(wr * 32 + 16 + l15) * LDP + ko];           \
    bf16x8 b0 = *(const bf16x8*)&Bsl[(wc * 32 + l15) * LDP + ko];                \
    bf16x8 b1 = *(const bf16x8*)&Bsl[(wc * 32 + 16 + l15) * LDP + ko];           \
    acc[0][0] = __builtin_amdgcn_mfma_f32_16x16x32_bf16(a0, b0, acc[0][0], 0, 0, 0); \
    acc[0][1] = __builtin_amdgcn_mfma_f32_16x16x32_bf16(a0, b1, acc[0][1], 0, 0, 0); \
    acc[1][0] = __builtin_amdgcn_mfma_f32_16x16x32_bf16(a1, b0, acc[1][0], 0, 0, 0); \
    acc[1][1] = __builtin_amdgcn_mfma_f32_16x16x32_bf16(a1, b1, acc[1][1], 0, 0, 0); \
  }

// ---------------- generic GEMM + bias -----------------------------------------
__global__ __launch_bounds__(256) void k_gemm_bias(
    const __hip_bfloat16* __restrict__ A, const __hip_bfloat16* __restrict__ W,
    const float* __restrict__ bias, float* __restrict__ C, int ldc) {
  __shared__ __align__(16) ushort Asl[64 * LDP];
  __shared__ __align__(16) ushort Bsl[64 * LDP];
  const int cb = blockIdx.x * 64, rb = blockIdx.y * 64;
  MFMA_TILE_BODY((const ushort*)A, (const ushort*)W, rb, cb)
  #pragma unroll
  for (int m = 0; m < 2; m++)
    #pragma unroll
    for (int n = 0; n < 2; n++) {
      int col = cb + wc * 32 + n * 16 + l15;
      float bv = bias[col];
      #pragma unroll
      for (int r = 0; r < 4; r++) {
        int row = rb + wr * 32 + m * 16 + l4 * 4 + r;
        C[(size_t)row * ldc + col] = acc[m][n][r] + bv;
      }
    }
}

// ---------------- vocab GEMM + fused chunk logsumexp + gold -------------------
__global__ __launch_bounds__(256) void k_vocab_mfma(
    const __hip_bfloat16* __restrict__ outs_bf, const __hip_bfloat16* __restrict__ Wv,
    const int* __restrict__ tgt, float* __restrict__ part_max,
    float* __restrict__ part_sum, float* __restrict__ gold) {
  __shared__ __align__(16) ushort Asl[64 * LDP];
  __shared__ __align__(16) ushort Bsl[64 * LDP];
  __shared__ int goldcol[64];
  __shared__ float pm[64][2], ps[64][2];
  const int by = blockIdx.x, vb = blockIdx.y;
  const int cb = vb * 64, rb = by * 64;
  if (threadIdx.x < 64) goldcol[threadIdx.x] = tgt[(by + 1) * B + threadIdx.x];
  MFMA_TILE_BODY((const ushort*)outs_bf, (const ushort*)Wv, rb, cb)
  #pragma unroll
  for (int m = 0; m < 2; m++) {
    #pragma unroll
    for (int r = 0; r < 4; r++) {
      int row_local = wr * 32 + m * 16 + l4 * 4 + r;
      int gc = goldcol[row_local];
      #pragma unroll
      for (int n = 0; n < 2; n++) {
        int col = cb + wc * 32 + n * 16 + l15;
        if (col == gc) gold[rb + row_local] = acc[m][n][r];
      }
      float v = fmaxf(acc[m][0][r], acc[m][1][r]);
      #pragma unroll
      for (int o = 1; o < 16; o <<= 1) v = fmaxf(v, __shfl_xor(v, o));
      float e = __expf(acc[m][0][r] - v) + __expf(acc[m][1][r] - v);
      #pragma unroll
      for (int o = 1; o < 16; o <<= 1) e += __shfl_xor(e, o);
      if (l15 == 0) { pm[row_local][wc] = v; ps[row_local][wc] = e; }
    }
  }
  __syncthreads();
  if (tid < 64) {
    float m0 = pm[tid][0], m1 = pm[tid][1];
    float M = fmaxf(m0, m1);
    float Ss = ps[tid][0] * __expf(m0 - M) + ps[tid][1] * __expf(m1 - M);
    int n = rb + tid;
    part_max[(size_t)n * NCHUNK + vb] = M;
    part_sum[(size_t)n * NCHUNK + vb] = Ss;
  }
}

// ---------------- encoder: 8 persistent blocks, LDS-stationary weights --------
// block id: dir = id>>2, js = id&3 (j0 = js*64). W_lds[col= g*64+jj][k], 256x264.
// Xenc: [par][dir][64][256] bf16. 1 barrier/step over the 4 blocks of a dir.
__global__ __launch_bounds__(512) void k_enc3(
    const float* __restrict__ XwF, const float* __restrict__ XwB,
    const float* __restrict__ WhhF, const float* __restrict__ WhhB,
    __hip_bfloat16* __restrict__ Xenc,
    __hip_bfloat16* __restrict__ fwd_bf, __hip_bfloat16* __restrict__ bwd_bf,
    float* __restrict__ Cfin, uint* __restrict__ cnt) {
  __shared__ __align__(16) ushort Wl[256 * 264];  // 135168 B
  const int id = blockIdx.x;
  const int dir = id >> 2, js = id & 3;
  const int j0 = js * 64;
  const int tid = threadIdx.x;
  const float* Whh = dir ? WhhB : WhhF;
  const float* Xw = dir ? XwB : XwF;
  for (int i = tid; i < 256 * 256; i += 512) {
    int col = i >> 8, k = i & 255;
    int g = col >> 6, jj = col & 63;
    Wl[col * 264 + k] = f2bu(Whh[(size_t)(g * 256 + j0 + jj) * 256 + k]);
  }
  const int lane = tid & 63, w = tid >> 6;
  const int l15 = lane & 15, l4 = lane >> 4;
  const int m = w >> 1, qp = w & 1;
  float c_reg[2][4];
  #pragma unroll
  for (int qi = 0; qi < 2; qi++)
    #pragma unroll
    for (int r = 0; r < 4; r++) c_reg[qi][r] = 0.f;
  __syncthreads();
  for (int st = 0; st < 64; st++) {
    const int ts = dir ? (63 - st) : st;
    const int par = st & 1;
    const ushort* Xr = (const ushort*)Xenc + (size_t)(par * 2 + dir) * 16384;
    ushort* Xo = (ushort*)Xenc + (size_t)(((par ^ 1) * 2) + dir) * 16384;
    f32x4 acc[2][4];
    #pragma unroll
    for (int qi = 0; qi < 2; qi++)
      #pragma unroll
      for (int g = 0; g < 4; g++) acc[qi][g] = (f32x4){0.f, 0.f, 0.f, 0.f};
    for (int kk = 0; kk < 8; kk++) {
      bf16x8 af = *(const bf16x8*)(Xr + (size_t)(m * 16 + l15) * 256 + kk * 32 + l4 * 8);
      #pragma unroll
      for (int qi = 0; qi < 2; qi++) {
        int q = 2 * qp + qi;
        #pragma unroll
        for (int g = 0; g < 4; g++) {
          bf16x8 bf = *(const bf16x8*)&Wl[(g * 64 + q * 16 + l15) * 264 + kk * 32 + l4 * 8];
          acc[qi][g] = __builtin_amdgcn_mfma_f32_16x16x32_bf16(af, bf, acc[qi][g], 0, 0, 0);
        }
      }
    }
    #pragma unroll
    for (int qi = 0; qi < 2; qi++) {
      int q = 2 * qp + qi;
      int jj = q * 16 + l15;
      int j = j0 + jj;
      #pragma unroll
      for (int r = 0; r < 4; r++) {
        int b = m * 16 + l4 * 4 + r;
        const float* xw = Xw + (size_t)(ts * 64 + b) * 1024;
        float zi = acc[qi][0][r] + xw[j];
        float zf = acc[qi][1][r] + xw[256 + j];
        float zg = acc[qi][2][r] + xw[512 + j];
        float zo = acc[qi][3][r] + xw[768 + j];
        float c = sigf(zf) * c_reg[qi][r] + sigf(zi) * tanhfast(zg);
        c_reg[qi][r] = c;
        float h = sigf(zo) * tanhfast(c);
        ushort hb = f2bu(h);
        Xo[(size_t)b * 256 + j] = hb;
        if (dir == 0) ((ushort*)fwd_bf)[(size_t)(st * 64 + b) * 256 + j] = hb;
        else          ((ushort*)bwd_bf)[(size_t)((63 - st) * 64 + b) * 256 + j] = hb;
      }
    }
    g_barrier(&cnt[dir], 4u * (uint)(st + 1));
  }
  #pragma unroll
  for (int qi = 0; qi < 2; qi++) {
    int q = 2 * qp + qi;
    int jj = q * 16 + l15;
    #pragma unroll
    for (int r = 0; r < 4; r++) {
      int b = m * 16 + l4 * 4 + r;
      Cfin[(size_t)(dir * 64 + b) * 256 + j0 + jj] = c_reg[qi][r];
    }
  }
}

// ---------------- decoder init: reads final enc h from Xenc par0 --------------
__global__ __launch_bounds__(256) void k_dec_init2(
    const __hip_bfloat16* __restrict__ Xenc, const float* __restrict__ Cfin,
    const float* __restrict__ Wh, const float* __restrict__ Wc,
    float* __restrict__ dech0, float* __restrict__ decc0) {
  int b = blockIdx.x, tid = threadIdx.x;
  __shared__ __align__(16) float ch[512], cc[512];
  ch[tid]       = __bfloat162float(Xenc[(size_t)(0 * 64 + b) * 256 + tid]);
  ch[256 + tid] = __bfloat162float(Xenc[(size_t)(1 * 64 + b) * 256 + tid]);
  cc[tid]       = Cfin[(size_t)(0 * 64 + b) * 256 + tid];
  cc[256 + tid] = Cfin[(size_t)(1 * 64 + b) * 256 + tid];
  __syncthreads();
  const float* wh = Wh + tid * 512;
  const float* wc = Wc + tid * 512;
  float ah = 0, ac = 0;
  for (int k = 0; k < 512; k += 4) {
    float4 hv = *(const float4*)&ch[k];
    float4 cv = *(const float4*)&cc[k];
    float4 w1 = *(const float4*)&wh[k];
    float4 w2 = *(const float4*)&wc[k];
    ah += hv.x * w1.x + hv.y * w1.y + hv.z * w1.z + hv.w * w1.w;
    ac += cv.x * w2.x + cv.y * w2.y + cv.z * w2.z + cv.w * w2.w;
  }
  dech0[b * 256 + tid] = ah;
  decc0[b * 256 + tid] = ac;
}

// ---------------- enc_proj ----------------------------------------------------
__global__ __launch_bounds__(256) void k_enc_proj(
    const __hip_bfloat16* __restrict__ fwd_bf, const __hip_bfloat16* __restrict__ bwd_bf,
    const float* __restrict__ Watt, __hip_bfloat16* __restrict__ encproj_bf) {
  int b = blockIdx.x, s = blockIdx.y, tid = threadIdx.x;
  __shared__ __align__(16) float eh[512];
  eh[tid]       = __bfloat162float(fwd_bf[(s * B + b) * H + tid]);
  eh[256 + tid] = __bfloat162float(bwd_bf[(s * B + b) * H + tid]);
  __syncthreads();
  const float* w = Watt + tid * 512;
  float acc = 0;
  for (int k = 0; k < 512; k += 4) {
    float4 xv = *(const float4*)&eh[k];
    float4 wv = *(const float4*)&w[k];
    acc += xv.x * wv.x + xv.y * wv.y + xv.z * wv.z + xv.w * wv.w;
  }
  encproj_bf[(b * S + s) * H + tid] = __float2bfloat16(acc);
}

// ---------------- decoder: 136 persistent blocks ------------------------------
// id<8: z-block js=id (j0=32js): W_lds[col=g*32+jj][k 0..512], LSTM in-register.
// id>=8: att-block: aid=id-8, b=aid>>1, jh=aid&1: attention + Wcomb half.
// Xd: [par][64][512] bf16 ([h|O]). 2 barriers/step.
__global__ __launch_bounds__(512) void k_dec3(
    const float* __restrict__ YW, const float* __restrict__ dWih,
    const float* __restrict__ dWhh, const uint2* __restrict__ Wcq,
    const __hip_bfloat16* __restrict__ encproj_bf,
    const __hip_bfloat16* __restrict__ fwd_bf, const __hip_bfloat16* __restrict__ bwd_bf,
    const float* __restrict__ decc0, __hip_bfloat16* __restrict__ Xd_,
    __hip_bfloat16* __restrict__ outs_bf,
    uint* __restrict__ loc, uint* __restrict__ glob) {
  __shared__ __align__(16) char smem[136704];
  const int id = blockIdx.x;
  const int grp = id & 7;
  const int tid = threadIdx.x;
  ushort* Xd = (ushort*)Xd_;

  if (id < 8) {
    // ---------------- z-block ----------------
    ushort* Wl = (ushort*)smem;  // [128][520] = 133120 B
    const int js = id, j0 = js * 32;
    for (int i = tid; i < 128 * 512; i += 512) {
      int col = i >> 9, k = i & 511;
      int g = col >> 5, jj = col & 31;
      int gr = g * 256 + j0 + jj;
      float v = (k < 256) ? dWhh[(size_t)gr * 256 + k]
                          : dWih[(size_t)gr * 512 + 256 + (k - 256)];
      Wl[col * 520 + k] = f2bu(v);
    }
    const int lane = tid & 63, w = tid >> 6;
    const int l15 = lane & 15, l4 = lane >> 4;
    const int m = w >> 1, jjh = w & 1;
    const int jj = jjh * 16 + l15;
    float c_reg[4];
    #pragma unroll
    for (int r = 0; r < 4; r++) {
      int b = m * 16 + l4 * 4 + r;
      c_reg[r] = decc0[(size_t)b * 256 + j0 + jj];
    }
    __syncthreads();
    for (int t = 0; t < 63; t++) {
      const int par = t & 1;
      const ushort* Xr = Xd + (size_t)par * 32768;
      ushort* Xo = Xd + (size_t)(par ^ 1) * 32768;
      f32x4 acc[4];
      #pragma unroll
      for (int g = 0; g < 4; g++) acc[g] = (f32x4){0.f, 0.f, 0.f, 0.f};
      for (int kk = 0; kk < 16; kk++) {
        bf16x8 af = *(const bf16x8*)(Xr + (size_t)(m * 16 + l15) * 512 + kk * 32 + l4 * 8);
        #pragma unroll
        for (int g = 0; g < 4; g++) {
          bf16x8 bf = *(const bf16x8*)&Wl[(g * 32 + jjh * 16 + l15) * 520 + kk * 32 + l4 * 8];
          acc[g] = __builtin_amdgcn_mfma_f32_16x16x32_bf16(af, bf, acc[g], 0, 0, 0);
        }
      }
      #pragma unroll
      for (int r = 0; r < 4; r++) {
        int b = m * 16 + l4 * 4 + r;
        const float* yw = YW + (size_t)(t * 64 + b) * 1024;
        int j = j0 + jj;
        float zi = acc[0][r] + yw[j];
        float zf = acc[1][r] + yw[256 + j];
        float zg = acc[2][r] + yw[512 + j];
        float zo = acc[3][r] + yw[768 + j];
        float c = sigf(zf) * c_reg[r] + sigf(zi) * tanhfast(zg);
        c_reg[r] = c;
        float h = sigf(zo) * tanhfast(c);
        Xo[(size_t)b * 512 + j] = f2bu(h);
      }
      dbar(loc, glob, grp, 2 * t);
      dbar(loc, glob, grp, 2 * t + 1);
    }
  } else {
    // ---------------- attention block ----------------
    const int aid = id - 8;
    const int b = aid >> 1, jh = aid & 1;
    ushort* ep = (ushort*)smem;                       // [64][264] = 33792 B
    ushort* eh = (ushort*)(smem + 33792);             // [64][520] = 66560 B
    float* hn = (float*)(smem + 100352);              // 256 f
    float* xcomb = (float*)(smem + 101376);           // 768 f
    float* e_l = (float*)(smem + 104448);             // 64
    float* alpha_l = (float*)(smem + 104704);         // 64
    float* op_l = (float*)(smem + 104960);            // [4][128]
    for (int i = tid; i < 64 * 256; i += 512) {
      int s = i >> 8, k = i & 255;
      ep[s * 264 + k] = ((const ushort*)encproj_bf)[(size_t)(b * 64 + s) * 256 + k];
    }
    for (int i = tid; i < 64 * 512; i += 512) {
      int s = i >> 9, d = i & 511;
      ushort v = (d < 256) ? ((const ushort*)fwd_bf)[(size_t)(s * 64 + b) * 256 + d]
                           : ((const ushort*)bwd_bf)[(size_t)(s * 64 + b) * 256 + d - 256];
      eh[s * 520 + d] = v;
    }
    __syncthreads();
    for (int t = 0; t < 63; t++) {
      dbar(loc, glob, grp, 2 * t);  // wait for h(t)
      const ushort* Xh = Xd + (size_t)((t & 1) ^ 1) * 32768 + (size_t)b * 512;
      if (tid < 256) hn[tid] = __uint_as_float(((uint)Xh[tid]) << 16);
      __syncthreads();
      {  // e[s]
        int s = tid >> 3, q8 = tid & 7;
        const ushort* pr = ep + s * 264 + q8 * 32;
        const float* hq = hn + q8 * 32;
        float a = 0.f;
        #pragma unroll 8
        for (int kk = 0; kk < 32; kk += 2) {
          uint wv = *(const uint*)(pr + kk);
          a += bflo(wv) * hq[kk] + bfhi(wv) * hq[kk + 1];
        }
        a += __shfl_xor(a, 1);
        a += __shfl_xor(a, 2);
        a += __shfl_xor(a, 4);
        if (q8 == 0) e_l[s] = a;
      }
      __syncthreads();
      if (tid < 64) {
        float e = e_l[tid];
        float mx = e;
        #pragma unroll
        for (int o = 32; o > 0; o >>= 1) mx = fmaxf(mx, __shfl_xor(mx, o));
        float p = __expf(e - mx);
        float ss = p;
        #pragma unroll
        for (int o = 32; o > 0; o >>= 1) ss += __shfl_xor(ss, o);
        alpha_l[tid] = p / ss;
      }
      __syncthreads();
      {  // a_t[d]
        float a = 0.f;
        const ushort* col = eh + tid;
        #pragma unroll 8
        for (int s = 0; s < 64; s++)
          a += alpha_l[s] * __uint_as_float(((uint)col[s * 520]) << 16);
        xcomb[tid] = a;
        if (tid < 256) xcomb[512 + tid] = hn[tid];
      }
      __syncthreads();
      {  // O-half = tanh(xcomb . Wcomb^T) — stream Wcq quarter per k-slice
        int jl = tid & 127, kq = tid >> 7;
        int j = jh * 128 + jl;
        const uint2* wp = Wcq + (size_t)(kq * 48) * 256 + j;
        const float4* x4 = (const float4*)xcomb + kq * 48;
        float a = 0.f;
        #pragma unroll 6
        for (int ii = 0; ii < 48; ii++) {
          uint2 wv = wp[(size_t)ii * 256];
          float4 xv = x4[ii];
          a += bflo(wv.x) * xv.x + bfhi(wv.x) * xv.y + bflo(wv.y) * xv.z + bfhi(wv.y) * xv.w;
        }
        op_l[kq * 128 + jl] = a;
      }
      __syncthreads();
      if (tid < 128) {
        float sum = op_l[tid] + op_l[128 + tid] + op_l[256 + tid] + op_l[384 + tid];
        float O = tanhfast(sum);
        ushort Ob = f2bu(O);
        Xd[(size_t)((t & 1) ^ 1) * 32768 + (size_t)b * 512 + 256 + jh * 128 + tid] = Ob;
        ((ushort*)outs_bf)[(size_t)(t * 64 + b) * 256 + jh * 128 + tid] = Ob;
      }
      dbar(loc, glob, grp, 2 * t + 1);
    }
  }
}

// ---------------- final reduce ------------------------------------------------
__global__ __launch_bounds__(256) void k_final(
    const float* __restrict__ part_max, const float* __restrict__ part_sum,
    const float* __restrict__ gold, const int* __restrict__ tgt,
    float* __restrict__ out) {
  int b = blockIdx.x, tid = threadIdx.x;
  int tq = tid >> 2, q = tid & 3;
  __shared__ float lm[64][4], ls[64][4];
  __shared__ float red[64];
  if (tq < T - 1) {
    int n = tq * B + b;
    float m = -__builtin_inff(), s = 0;
    for (int i = q; i < NCHUNK; i += 4) {
      float pmv = part_max[(size_t)n * NCHUNK + i];
      float psv = part_sum[(size_t)n * NCHUNK + i];
      float M2 = fmaxf(m, pmv);
      s = s * __expf(m - M2) + psv * __expf(pmv - M2);
      m = M2;
    }
    lm[tq][q] = m;
    ls[tq][q] = s;
  }
  __syncthreads();
  if (tid < T - 1) {
    float M = fmaxf(fmaxf(lm[tid][0], lm[tid][1]), fmaxf(lm[tid][2], lm[tid][3]));
    float Ss = ls[tid][0] * __expf(lm[tid][0] - M) + ls[tid][1] * __expf(lm[tid][1] - M) +
               ls[tid][2] * __expf(lm[tid][2] - M) + ls[tid][3] * __expf(lm[tid][3] - M);
    float lse = M + logf(Ss);
    int g = tgt[(tid + 1) * B + b];
    red[tid] = (g != 0) ? (gold[tid * B + b] - lse) : 0.f;
  }
  if (tid == T - 1) red[T - 1] = 0.f;
  __syncthreads();
  if (tid == 0) {
    float s = 0;
    for (int i = 0; i < T - 1; i++) s += red[i];
    out[b] = s;
  }
}

extern "C" void kernel_launch(void* const* d_in, const int* in_sizes, int n_in,
                              void* d_out, int out_size, void* d_ws, size_t ws_size,
                              hipStream_t stream) {
  (void)in_sizes; (void)n_in; (void)out_size; (void)ws_size;
  const int*   src   = (const int*)  d_in[0];
  const int*   tgt   = (const int*)  d_in[1];
  const float* semb  = (const float*)d_in[2];
  const float* temb  = (const float*)d_in[3];
  const float* WihF  = (const float*)d_in[4];
  const float* WhhF  = (const float*)d_in[5];
  const float* bF    = (const float*)d_in[6];
  const float* WihB  = (const float*)d_in[7];
  const float* WhhB  = (const float*)d_in[8];
  const float* bB    = (const float*)d_in[9];
  const float* dWih  = (const float*)d_in[10];
  const float* dWhh  = (const float*)d_in[11];
  const float* db    = (const float*)d_in[12];
  const float* Wh    = (const float*)d_in[13];
  const float* Wc    = (const float*)d_in[14];
  const float* Watt  = (const float*)d_in[15];
  const float* Wcomb = (const float*)d_in[16];
  const float* Wv    = (const float*)d_in[17];
  float* out = (float*)d_out;

  char* wp = (char*)d_ws;
  auto alloc = [&](size_t bytes) -> char* {
    char* p = wp;
    wp += (bytes + 255) & ~(size_t)255;
    return p;
  };
  float* XwF  = (float*)alloc((size_t)S * B * H4 * 4);
  float* XwB  = (float*)alloc((size_t)S * B * H4 * 4);
  float* YW   = (float*)alloc((size_t)(T - 1) * B * H4 * 4);
  __hip_bfloat16* fwd_bf     = (__hip_bfloat16*)alloc((size_t)S * B * H * 2);
  __hip_bfloat16* bwd_bf     = (__hip_bfloat16*)alloc((size_t)S * B * H * 2);
  __hip_bfloat16* encproj_bf = (__hip_bfloat16*)alloc((size_t)B * S * H * 2);
  __hip_bfloat16* Ag         = (__hip_bfloat16*)alloc((size_t)S * B * E * 2);
  __hip_bfloat16* Yg         = (__hip_bfloat16*)alloc((size_t)(T - 1) * B * E * 2);
  __hip_bfloat16* WihF_bf    = (__hip_bfloat16*)alloc((size_t)H4 * E * 2);
  __hip_bfloat16* WihB_bf    = (__hip_bfloat16*)alloc((size_t)H4 * E * 2);
  __hip_bfloat16* dWih_bf    = (__hip_bfloat16*)alloc((size_t)H4 * E * 2);
  __hip_bfloat16* Wv_bf      = (__hip_bfloat16*)alloc((size_t)V * H * 2);
  __hip_bfloat16* outs_bf    = (__hip_bfloat16*)alloc((size_t)NROW * H * 2);
  uint2* Wcq = (uint2*)alloc((size_t)192 * 256 * 8);
  float* part_max = (float*)alloc((size_t)NROW * NCHUNK * 4);
  float* part_sum = (float*)alloc((size_t)NROW * NCHUNK * 4);
  float* gold     = (float*)alloc((size_t)NROW * 4);
  float* Cfin  = (float*)alloc((size_t)2 * B * H * 4);
  float* dech0 = (float*)alloc((size_t)B * H * 4);
  float* decc0 = (float*)alloc((size_t)B * H * 4);
  __hip_bfloat16* Xenc = (__hip_bfloat16*)alloc((size_t)2 * 2 * B * H * 2);  // [par][dir][b][j]
  __hip_bfloat16* Xdec = (__hip_bfloat16*)alloc((size_t)2 * B * 512 * 2);    // [par][b][h|O]
  // state: barrier counters, zeroed every call
  char* stateBase = wp;
  uint* cnt_enc = (uint*)alloc(2 * 4);
  uint* loc_dec = (uint*)alloc(8 * 4);
  uint* glob_dec = (uint*)alloc(4);
  size_t stateBytes = (size_t)(wp - stateBase);
  hipMemsetAsync(stateBase, 0, stateBytes, stream);
  hipMemsetAsync(Xenc, 0, (size_t)2 * 2 * B * H * 2, stream);

  // converts + gathers + Wcomb pack
  hipLaunchKernelGGL(k_cvt_bf16, dim3((H4 * E + 255) / 256), dim3(256), 0, stream,
                     WihF, WihF_bf, H4 * E);
  hipLaunchKernelGGL(k_cvt_bf16, dim3((H4 * E + 255) / 256), dim3(256), 0, stream,
                     WihB, WihB_bf, H4 * E);
  hipLaunchKernelGGL(k_cvt_slice, dim3(H4), dim3(256), 0, stream, dWih, dWih_bf);
  hipLaunchKernelGGL(k_cvt_bf16, dim3((V * H + 255) / 256), dim3(256), 0, stream,
                     Wv, Wv_bf, V * H);
  hipLaunchKernelGGL(k_gather, dim3(S * B), dim3(256), 0, stream, src, semb, Ag);
  hipLaunchKernelGGL(k_gather, dim3((T - 1) * B), dim3(256), 0, stream, tgt, temb, Yg);
  hipLaunchKernelGGL(k_pack4, dim3(192 * 256 / 256), dim3(256), 0, stream,
                     Wcomb, Wcq, 192 * 256, 8, 768, 0);

  // input GEMMs (MFMA)
  hipLaunchKernelGGL(k_gemm_bias, dim3(H4 / 64, S * B / 64), dim3(256), 0, stream,
                     Ag, WihF_bf, bF, XwF, H4);
  hipLaunchKernelGGL(k_gemm_bias, dim3(H4 / 64, S * B / 64), dim3(256), 0, stream,
                     Ag, WihB_bf, bB, XwB, H4);
  hipLaunchKernelGGL(k_gemm_bias, dim3(H4 / 64, (T - 1) * B / 64), dim3(256), 0, stream,
                     Yg, dWih_bf, db, YW, H4);

  // encoder: 8 persistent blocks, stationary weights
  hipLaunchKernelGGL(k_enc3, dim3(8), dim3(512), 0, stream,
                     XwF, XwB, WhhF, WhhB, Xenc, fwd_bf, bwd_bf, Cfin, cnt_enc);
  hipLaunchKernelGGL(k_dec_init2, dim3(B), dim3(256), 0, stream,
                     Xenc, Cfin, Wh, Wc, dech0, decc0);
  hipLaunchKernelGGL(k_xdec_init, dim3(B), dim3(256), 0, stream, dech0, Xdec);
  hipLaunchKernelGGL(k_enc_proj, dim3(B, S), dim3(256), 0, stream,
                     fwd_bf, bwd_bf, Watt, encproj_bf);

  // decoder: 136 persistent blocks (8 z + 128 attention)
  hipLaunchKernelGGL(k_dec3, dim3(136), dim3(512), 0, stream,
                     YW, dWih, dWhh, Wcq, encproj_bf, fwd_bf, bwd_bf,
                     decc0, Xdec, outs_bf, loc_dec, glob_dec);

  // vocab projection + log-softmax partials + final reduce
  hipLaunchKernelGGL(k_vocab_mfma, dim3(T - 1, NCHUNK), dim3(256), 0, stream,
                     outs_bf, Wv_bf, tgt, part_max, part_sum, gold);
  hipLaunchKernelGGL(k_final, dim3(B), dim3(256), 0, stream,
                     part_max, part_sum, gold, tgt, out);
}